// Round 14
// baseline (185.399 us; speedup 1.0000x reference)
//
#include <hip/hip_runtime.h>
#include <hip/hip_bf16.h>

// ---------------------------------------------------------------------------
// Net_MP: two NNConv layers (2->32, 32->32) + Linear(32->1) on a graph.
// R14: NO f32 atomics. Counting-bucket CSR by dst (CAP=32, int atomics only),
// edge kernels write dense per-edge msg rows [E,32] (coalesced), per-dst
// gather-sum kernels reduce bucket lists. agg2 never materialized (fused).
//   memset(cnt) -> edge1_dense(+bucket build) -> agg1 -> edge2_dense -> agg2
// ---------------------------------------------------------------------------

typedef __attribute__((ext_vector_type(8))) short short8;   // 8 bf16
typedef __attribute__((ext_vector_type(4))) float f32x4;

union frag_u { short8 s; unsigned u[4]; };

__device__ inline unsigned cvt_pk2(float lo, float hi) {
    union { __hip_bfloat162 h; unsigned u; } c;
    c.h = __float22bfloat162_rn(make_float2(lo, hi));   // v_cvt_pk_bf16_f32
    return c.u;
}
__device__ inline float relu(float v) { return v > 0.f ? v : 0.f; }

#define CAP 32   // bucket capacity per dst; Poisson(4) => P(overflow) ~ 0

// ====== conv1 edge phase: dst-bucket build + dense msg1 [E,32] =============
__global__ __launch_bounds__(256, 4) void edge1_dense(
    const float* __restrict__ x,    // [N,2]
    const int*   __restrict__ ei,   // [2,E]
    const float* __restrict__ ea,   // [E,2]
    const float* __restrict__ w1,   // [2,16]
    const float* __restrict__ b1,   // [16]
    const float* __restrict__ w2,   // [16,64] = [16][2][32]
    const float* __restrict__ b2,   // [64] = [2][32]
    int*   __restrict__ cnt,        // [N] (zeroed)
    int*   __restrict__ bucket,     // [N*CAP]
    float* __restrict__ msg,        // [E,32]
    int E)
{
    const int tid  = threadIdx.x;
    const int lane = tid & 63;
    const int wv   = tid >> 6;
    const int nh   = wv & 1;
    const int gsel = wv >> 1;
    const int r16  = lane & 15;
    const int g    = lane >> 4;
    const int oo   = nh * 16 + r16;
    const int g8   = g * 8;

    // B fragments
    short8 bf0, bf1;
    {
        frag_u f;
#pragma unroll
        for (int wd = 0; wd < 4; ++wd) {
            int kk0 = g8 + 2 * wd, kk1 = kk0 + 1;
            f.u[wd] = cvt_pk2(w2[(kk0 >> 1) * 64 + (kk0 & 1) * 32 + oo],
                              w2[(kk1 >> 1) * 64 + (kk1 & 1) * 32 + oo]);
        }
        bf0 = f.s;
        f.u[0] = (g == 0) ? cvt_pk2(b2[oo], b2[32 + oo]) : 0u;
        f.u[1] = 0u; f.u[2] = 0u; f.u[3] = 0u;
        bf1 = f.s;
    }

    const float4 w1a = *(const float4*)(w1 + g * 4);
    const float4 w1b = *(const float4*)(w1 + 16 + g * 4);
    const float4 b1v = *(const float4*)(b1 + g * 4);

    const int pairs = (E + 31) >> 5;
    const int G = gridDim.x;
    for (int p = blockIdx.x; p < pairs; p += G) {
        // ---- bucket insert: one lane per edge of this 32-edge tile ----
        if (tid < 32) {
            int e = p * 32 + tid;
            if (e < E) {
                int dst  = ei[E + e];
                int slot = atomicAdd(&cnt[dst], 1);
                if (slot < CAP) bucket[dst * CAP + slot] = e;
            }
        }

        const int base = p * 32 + gsel * 16;
        const int edge = base + r16;
        const bool ev = edge < E;
        const int ec = ev ? edge : 0;

        int    src = ei[ec];
        float2 eav = *(const float2*)(ea + 2 * (size_t)ec);
        float2 xv  = *(const float2*)(x + 2 * (size_t)src);
        if (!ev) xv = make_float2(0.f, 0.f);

        float he0 = relu(fmaf(eav.x, w1a.x, fmaf(eav.y, w1b.x, b1v.x)));
        float he1 = relu(fmaf(eav.x, w1a.y, fmaf(eav.y, w1b.y, b1v.y)));
        float he2 = relu(fmaf(eav.x, w1a.z, fmaf(eav.y, w1b.z, b1v.z)));
        float he3 = relu(fmaf(eav.x, w1a.w, fmaf(eav.y, w1b.w, b1v.w)));

        frag_u a;
        a.u[0] = cvt_pk2(he0 * xv.x, he0 * xv.y);
        a.u[1] = cvt_pk2(he1 * xv.x, he1 * xv.y);
        a.u[2] = cvt_pk2(he2 * xv.x, he2 * xv.y);
        a.u[3] = cvt_pk2(he3 * xv.x, he3 * xv.y);
        f32x4 acc = {0.f, 0.f, 0.f, 0.f};
        acc = __builtin_amdgcn_mfma_f32_16x16x32_bf16(a.s, bf0, acc, 0, 0, 0);

        a.u[0] = (g == 0) ? cvt_pk2(xv.x, xv.y) : 0u;
        a.u[1] = 0u; a.u[2] = 0u; a.u[3] = 0u;
        acc = __builtin_amdgcn_mfma_f32_16x16x32_bf16(a.s, bf1, acc, 0, 0, 0);

        // dense store: msg[(base+g*4+j)*32 + oo]; 16 r16-lanes = 64B runs
#pragma unroll
        for (int j = 0; j < 4; ++j) {
            int eg = base + g * 4 + j;
            if (eg < E) msg[(size_t)eg * 32 + oo] = acc[j];
        }
    }
}

// ====== agg1: per-dst sum of msg rows (no atomics) =========================
__global__ __launch_bounds__(256, 8) void agg1_kernel(
    const int*   __restrict__ cnt,
    const int*   __restrict__ bucket,
    const float* __restrict__ msg,   // [E,32]
    float* __restrict__ agg1,        // [N,32]
    int N)
{
    int gid = blockIdx.x * blockDim.x + threadIdx.x;
    int n = gid >> 5, o = gid & 31;
    if (n >= N) return;
    int cn = min(cnt[n], CAP);
    float s = 0.f;
    for (int k = 0; k < cn; ++k) {
        int e = bucket[n * CAP + k];
        s += msg[(size_t)e * 32 + o];    // 32 lanes -> 128B coalesced row
    }
    agg1[(size_t)n * 32 + o] = s;
}

// ====== conv2 edge phase (K = 544), node1 fused, dense msg2 ================
__global__ __launch_bounds__(256, 4) void edge2_dense(
    const float* __restrict__ x,     // [N,2]
    const float* __restrict__ agg1,  // [N,32]
    const int*   __restrict__ ei,    // [2,E]
    const float* __restrict__ ea,    // [E,2]
    const float* __restrict__ root1, // [2,32]
    const float* __restrict__ bias1, // [32]
    const float* __restrict__ w1,    // nn2_w1 [2,16]
    const float* __restrict__ b1,    // nn2_b1 [16]
    const float* __restrict__ w2,    // nn2_w2 [16,1024]
    const float* __restrict__ b2,    // nn2_b2 [1024]
    float* __restrict__ msg,         // [E,32]
    int E)
{
    const int tid  = threadIdx.x;
    const int lane = tid & 63;
    const int wv   = tid >> 6;
    const int nh   = wv & 1;
    const int gsel = wv >> 1;
    const int r16  = lane & 15;
    const int g    = lane >> 4;
    const int oo   = nh * 16 + r16;
    const int g8   = g * 8;

    short8 bfrag[17];
#pragma unroll
    for (int t = 0; t < 16; ++t) {
        frag_u f;
#pragma unroll
        for (int wd = 0; wd < 4; ++wd) {
            int i0 = g8 + 2 * wd;
            f.u[wd] = cvt_pk2(w2[t * 1024 + i0 * 32 + oo],
                              w2[t * 1024 + (i0 + 1) * 32 + oo]);
        }
        bfrag[t] = f.s;
    }
    {
        frag_u f;
#pragma unroll
        for (int wd = 0; wd < 4; ++wd) {
            int i0 = g8 + 2 * wd;
            f.u[wd] = cvt_pk2(b2[i0 * 32 + oo], b2[(i0 + 1) * 32 + oo]);
        }
        bfrag[16] = f.s;
    }

    const float4 r0a = *(const float4*)(root1 + g8);
    const float4 r0b = *(const float4*)(root1 + g8 + 4);
    const float4 r1a = *(const float4*)(root1 + 32 + g8);
    const float4 r1b = *(const float4*)(root1 + 32 + g8 + 4);
    const float4 b1a = *(const float4*)(bias1 + g8);
    const float4 b1b = *(const float4*)(bias1 + g8 + 4);

    float w1r0[16], w1r1[16], b1r[16];
#pragma unroll
    for (int k = 0; k < 16; ++k) {
        w1r0[k] = w1[k]; w1r1[k] = w1[16 + k]; b1r[k] = b1[k];
    }

    const int pairs = (E + 31) >> 5;
    const int G = gridDim.x;
    for (int p = blockIdx.x; p < pairs; p += G) {
        const int base = p * 32 + gsel * 16;
        const int edge = base + r16;
        const bool ev = edge < E;
        const int ec = ev ? edge : 0;

        int    src = ei[ec];
        float2 eav = *(const float2*)(ea + 2 * (size_t)ec);
        float2 xv  = *(const float2*)(x + 2 * (size_t)src);
        float4 aA  = *(const float4*)(agg1 + (size_t)src * 32 + g8);
        float4 aB  = *(const float4*)(agg1 + (size_t)src * 32 + g8 + 4);

        float4 hA, hB;
        hA.x = relu(aA.x + xv.x * r0a.x + xv.y * r1a.x + b1a.x);
        hA.y = relu(aA.y + xv.x * r0a.y + xv.y * r1a.y + b1a.y);
        hA.z = relu(aA.z + xv.x * r0a.z + xv.y * r1a.z + b1a.z);
        hA.w = relu(aA.w + xv.x * r0a.w + xv.y * r1a.w + b1a.w);
        hB.x = relu(aB.x + xv.x * r0b.x + xv.y * r1b.x + b1b.x);
        hB.y = relu(aB.y + xv.x * r0b.y + xv.y * r1b.y + b1b.y);
        hB.z = relu(aB.z + xv.x * r0b.z + xv.y * r1b.z + b1b.z);
        hB.w = relu(aB.w + xv.x * r0b.w + xv.y * r1b.w + b1b.w);
        if (!ev) { hA = make_float4(0.f,0.f,0.f,0.f); hB = make_float4(0.f,0.f,0.f,0.f); }

        const float eax = eav.x, eay = eav.y;
        f32x4 acc = {0.f, 0.f, 0.f, 0.f};
#pragma unroll
        for (int t = 0; t < 16; ++t) {
            float he = relu(fmaf(eax, w1r0[t], fmaf(eay, w1r1[t], b1r[t])));
            frag_u a;
            a.u[0] = cvt_pk2(he * hA.x, he * hA.y);
            a.u[1] = cvt_pk2(he * hA.z, he * hA.w);
            a.u[2] = cvt_pk2(he * hB.x, he * hB.y);
            a.u[3] = cvt_pk2(he * hB.z, he * hB.w);
            acc = __builtin_amdgcn_mfma_f32_16x16x32_bf16(a.s, bfrag[t], acc, 0, 0, 0);
        }
        {
            frag_u a;
            a.u[0] = cvt_pk2(hA.x, hA.y);
            a.u[1] = cvt_pk2(hA.z, hA.w);
            a.u[2] = cvt_pk2(hB.x, hB.y);
            a.u[3] = cvt_pk2(hB.z, hB.w);
            acc = __builtin_amdgcn_mfma_f32_16x16x32_bf16(a.s, bfrag[16], acc, 0, 0, 0);
        }

#pragma unroll
        for (int j = 0; j < 4; ++j) {
            int eg = base + g * 4 + j;
            if (eg < E) msg[(size_t)eg * 32 + oo] = acc[j];
        }
    }
}

// ====== agg2 + node2 + fc2 fused (no agg2 buffer, no atomics) ==============
__global__ __launch_bounds__(256, 8) void agg2_node2(
    const float* __restrict__ x,     // [N,2]
    const float* __restrict__ agg1,  // [N,32]
    const int*   __restrict__ cnt,
    const int*   __restrict__ bucket,
    const float* __restrict__ msg,   // [E,32]
    const float* __restrict__ root1, // [2,32]
    const float* __restrict__ bias1, // [32]
    const float* __restrict__ root2, // [32,32]
    const float* __restrict__ bias2, // [32]
    const float* __restrict__ fc2w,  // [32,1]
    const float* __restrict__ fc2b,  // [1]
    float* __restrict__ out,         // [N]
    int N)
{
    __shared__ float s_r[1024];
    for (int t = threadIdx.x; t < 1024; t += blockDim.x) s_r[t] = root2[t];
    __syncthreads();

    int gid = blockIdx.x * blockDim.x + threadIdx.x;
    int n = gid >> 5, o = gid & 31;
    if (n >= N) return;

    // agg2 sum for (n,o)
    int cn = min(cnt[n], CAP);
    float v = bias2[o];
    for (int k = 0; k < cn; ++k) {
        int e = bucket[n * CAP + k];
        v += msg[(size_t)e * 32 + o];
    }

    // h1[n][o] recomputed (node1 fused)
    float2 xv = *(const float2*)(x + 2 * (size_t)n);
    float h1o = relu(agg1[(size_t)n * 32 + o]
                   + xv.x * root1[o] + xv.y * root1[32 + o] + bias1[o]);

#pragma unroll
    for (int i = 0; i < 32; ++i) {
        float hi = __shfl(h1o, i, 32);
        v = fmaf(hi, s_r[i * 32 + o], v);
    }
    v = relu(v);
    v *= fc2w[o];
#pragma unroll
    for (int off = 16; off; off >>= 1) v += __shfl_xor(v, off, 32);
    if (o == 0) out[n] = v + fc2b[0];
}

extern "C" void kernel_launch(void* const* d_in, const int* in_sizes, int n_in,
                              void* d_out, int out_size, void* d_ws, size_t ws_size,
                              hipStream_t stream) {
    const float* x      = (const float*)d_in[0];
    const int*   ei     = (const int*)  d_in[1];
    const float* ea     = (const float*)d_in[2];
    const float* nn1_w1 = (const float*)d_in[3];
    const float* nn1_b1 = (const float*)d_in[4];
    const float* nn1_w2 = (const float*)d_in[5];
    const float* nn1_b2 = (const float*)d_in[6];
    const float* root1  = (const float*)d_in[7];
    const float* bias1  = (const float*)d_in[8];
    const float* nn2_w1 = (const float*)d_in[9];
    const float* nn2_b1 = (const float*)d_in[10];
    const float* nn2_w2 = (const float*)d_in[11];
    const float* nn2_b2 = (const float*)d_in[12];
    const float* root2  = (const float*)d_in[13];
    const float* bias2  = (const float*)d_in[14];
    const float* fc2w   = (const float*)d_in[15];
    const float* fc2b   = (const float*)d_in[16];

    const int N = in_sizes[0] / 2;
    const int E = in_sizes[2] / 2;

    // ws layout: cnt[N] | bucket[N*CAP] | msg[E*32] | agg1[N*32]
    int*   cnt    = (int*)d_ws;
    int*   bucket = cnt + N;
    float* msg    = (float*)(bucket + (size_t)N * CAP);
    float* agg1   = msg + (size_t)E * 32;

    hipMemsetAsync(cnt, 0, (size_t)N * sizeof(int), stream);

    edge1_dense<<<1024, 256, 0, stream>>>(
        x, ei, ea, nn1_w1, nn1_b1, nn1_w2, nn1_b2, cnt, bucket, msg, E);

    agg1_kernel<<<(N * 32 + 255) / 256, 256, 0, stream>>>(
        cnt, bucket, msg, agg1, N);

    edge2_dense<<<1024, 256, 0, stream>>>(
        x, agg1, ei, ea, root1, bias1,
        nn2_w1, nn2_b1, nn2_w2, nn2_b2, msg, E);

    agg2_node2<<<(N * 32 + 255) / 256, 256, 0, stream>>>(
        x, agg1, cnt, bucket, msg, root1, bias1, root2, bias2, fc2w, fc2b,
        (float*)d_out, N);
}

// Round 15
// 166.615 us; speedup vs baseline: 1.1127x; 1.1127x over previous
//
#include <hip/hip_runtime.h>
#include <hip/hip_bf16.h>

// ---------------------------------------------------------------------------
// Net_MP: two NNConv layers (2->32, 32->32) + Linear(32->1) on a graph.
// Edge phases: per-edge outer-product u[e] (K = 16*IN + IN) contracted with a
// shared WrT[K,32] via bf16 MFMA; A-fragments built directly in registers.
// node1 fused into edge2/node2 (no h1 buffer). Simple loop bodies (software
// pipelining measured neutral; higher grids measured negative).
// R15 = best-measured config: edge grids 1024, lb(256,4), atomic scatter.
// ---------------------------------------------------------------------------

typedef __attribute__((ext_vector_type(8))) short short8;   // 8 bf16
typedef __attribute__((ext_vector_type(4))) float f32x4;

union frag_u { short8 s; unsigned u[4]; };

__device__ inline unsigned cvt_pk2(float lo, float hi) {
    union { __hip_bfloat162 h; unsigned u; } c;
    c.h = __float22bfloat162_rn(make_float2(lo, hi));   // v_cvt_pk_bf16_f32
    return c.u;
}
__device__ inline float relu(float v) { return v > 0.f ? v : 0.f; }

// ============ conv2 edge phase (K = 544), node1 fused in ===================
__global__ __launch_bounds__(256, 4) void edge2_fused(
    const float* __restrict__ x,     // [N,2]
    const float* __restrict__ agg1,  // [N,32] (conv1 aggregate, complete)
    const int*   __restrict__ ei,    // [2,E]
    const float* __restrict__ ea,    // [E,2]
    const float* __restrict__ root1, // [2,32]
    const float* __restrict__ bias1, // [32]
    const float* __restrict__ w1,    // nn2_w1 [2,16]
    const float* __restrict__ b1,    // nn2_b1 [16]
    const float* __restrict__ w2,    // nn2_w2 [16,1024] = [16][32in][32out]
    const float* __restrict__ b2,    // nn2_b2 [1024] = [32in][32out]
    float* __restrict__ agg,         // [N,32] atomic accum (agg2)
    int E)
{
    const int tid  = threadIdx.x;
    const int lane = tid & 63;
    const int wv   = tid >> 6;          // 0..3
    const int nh   = wv & 1;            // output half (16 cols)
    const int gsel = wv >> 1;           // edge-group within pair
    const int r16  = lane & 15;
    const int g    = lane >> 4;         // k-slice / D row-quad
    const int oo   = nh * 16 + r16;     // my output column
    const int g8   = g * 8;

    // ---- one-time: B fragments from global (w2 is L2-resident) ----
    short8 bfrag[17];
#pragma unroll
    for (int t = 0; t < 16; ++t) {
        frag_u f;
#pragma unroll
        for (int wd = 0; wd < 4; ++wd) {
            int i0 = g8 + 2 * wd;
            f.u[wd] = cvt_pk2(w2[t * 1024 + i0 * 32 + oo],
                              w2[t * 1024 + (i0 + 1) * 32 + oo]);
        }
        bfrag[t] = f.s;
    }
    {   // bias rows: kk = 512 + i  ->  b2[i*32 + oo]
        frag_u f;
#pragma unroll
        for (int wd = 0; wd < 4; ++wd) {
            int i0 = g8 + 2 * wd;
            f.u[wd] = cvt_pk2(b2[i0 * 32 + oo], b2[(i0 + 1) * 32 + oo]);
        }
        bfrag[16] = f.s;
    }

    // ---- node1 constants for my input slice j = g8..g8+7 ----
    const float4 r0a = *(const float4*)(root1 + g8);
    const float4 r0b = *(const float4*)(root1 + g8 + 4);
    const float4 r1a = *(const float4*)(root1 + 32 + g8);
    const float4 r1b = *(const float4*)(root1 + 32 + g8 + 4);
    const float4 b1a = *(const float4*)(bias1 + g8);
    const float4 b1b = *(const float4*)(bias1 + g8 + 4);

    // ---- edge-MLP weights (uniform) ----
    float w1r0[16], w1r1[16], b1r[16];
#pragma unroll
    for (int k = 0; k < 16; ++k) {
        w1r0[k] = w1[k]; w1r1[k] = w1[16 + k]; b1r[k] = b1[k];
    }

    const int pairs = (E + 31) >> 5;    // 32 edges per block-iter (2 groups)
    for (int p = blockIdx.x; p < pairs; p += gridDim.x) {
        const int base = p * 32 + gsel * 16;
        const int edge = base + r16;
        const bool ev  = edge < E;
        const int ec   = ev ? edge : 0;

        int    src = ei[ec];
        float2 eav = *(const float2*)(ea + 2 * (size_t)ec);
        float2 xv  = *(const float2*)(x + 2 * (size_t)src);
        float4 aA  = *(const float4*)(agg1 + (size_t)src * 32 + g8);
        float4 aB  = *(const float4*)(agg1 + (size_t)src * 32 + g8 + 4);

        // ---- node1 fused: h1[src][g8..g8+7] ----
        float4 hA, hB;
        hA.x = relu(aA.x + xv.x * r0a.x + xv.y * r1a.x + b1a.x);
        hA.y = relu(aA.y + xv.x * r0a.y + xv.y * r1a.y + b1a.y);
        hA.z = relu(aA.z + xv.x * r0a.z + xv.y * r1a.z + b1a.z);
        hA.w = relu(aA.w + xv.x * r0a.w + xv.y * r1a.w + b1a.w);
        hB.x = relu(aB.x + xv.x * r0b.x + xv.y * r1b.x + b1b.x);
        hB.y = relu(aB.y + xv.x * r0b.y + xv.y * r1b.y + b1b.y);
        hB.z = relu(aB.z + xv.x * r0b.z + xv.y * r1b.z + b1b.z);
        hB.w = relu(aB.w + xv.x * r0b.w + xv.y * r1b.w + b1b.w);
        if (!ev) { hA = make_float4(0.f,0.f,0.f,0.f); hB = make_float4(0.f,0.f,0.f,0.f); }

        // ---- MFMA chain over K = 544; he[t] computed in-loop ----
        const float eax = eav.x, eay = eav.y;
        f32x4 acc = {0.f, 0.f, 0.f, 0.f};
#pragma unroll
        for (int t = 0; t < 16; ++t) {
            float he = relu(fmaf(eax, w1r0[t], fmaf(eay, w1r1[t], b1r[t])));
            frag_u a;
            a.u[0] = cvt_pk2(he * hA.x, he * hA.y);
            a.u[1] = cvt_pk2(he * hA.z, he * hA.w);
            a.u[2] = cvt_pk2(he * hB.x, he * hB.y);
            a.u[3] = cvt_pk2(he * hB.z, he * hB.w);
            acc = __builtin_amdgcn_mfma_f32_16x16x32_bf16(a.s, bfrag[t], acc, 0, 0, 0);
        }
        {   // bias rows: u[512+i] = hsrc[i]
            frag_u a;
            a.u[0] = cvt_pk2(hA.x, hA.y);
            a.u[1] = cvt_pk2(hA.z, hA.w);
            a.u[2] = cvt_pk2(hB.x, hB.y);
            a.u[3] = cvt_pk2(hB.z, hB.w);
            acc = __builtin_amdgcn_mfma_f32_16x16x32_bf16(a.s, bfrag[16], acc, 0, 0, 0);
        }

        // ---- scatter: D row r = g*4+j -> edge base+g*4+j, col = oo ----
        float* ap = agg + oo;
        if (base + g * 4 + 3 < E) {
            int4 d4 = *(const int4*)(ei + (size_t)E + base + g * 4);
            atomicAdd(ap + (size_t)d4.x * 32, acc[0]);
            atomicAdd(ap + (size_t)d4.y * 32, acc[1]);
            atomicAdd(ap + (size_t)d4.z * 32, acc[2]);
            atomicAdd(ap + (size_t)d4.w * 32, acc[3]);
        } else {
#pragma unroll
            for (int j = 0; j < 4; ++j) {
                int eg = base + g * 4 + j;
                if (eg < E) atomicAdd(ap + (size_t)ei[E + eg] * 32, acc[j]);
            }
        }
    }
}

// ======================= conv1 edge phase (K = 64) =========================
__global__ __launch_bounds__(256, 4) void edge1_mfma(
    const float* __restrict__ x,    // [N,2]
    const int*   __restrict__ ei,
    const float* __restrict__ ea,
    const float* __restrict__ w1,   // [2,16]
    const float* __restrict__ b1,   // [16]
    const float* __restrict__ w2,   // [16,64] = [16][2][32]
    const float* __restrict__ b2,   // [64] = [2][32]
    float* __restrict__ agg,        // [N,32]
    int E)
{
    const int tid  = threadIdx.x;
    const int lane = tid & 63;
    const int wv   = tid >> 6;
    const int nh   = wv & 1;
    const int gsel = wv >> 1;
    const int r16  = lane & 15;
    const int g    = lane >> 4;
    const int oo   = nh * 16 + r16;
    const int g8   = g * 8;

    // B fragments
    short8 bf0, bf1;
    {
        frag_u f;
#pragma unroll
        for (int wd = 0; wd < 4; ++wd) {
            int kk0 = g8 + 2 * wd, kk1 = kk0 + 1;
            f.u[wd] = cvt_pk2(w2[(kk0 >> 1) * 64 + (kk0 & 1) * 32 + oo],
                              w2[(kk1 >> 1) * 64 + (kk1 & 1) * 32 + oo]);
        }
        bf0 = f.s;
        f.u[0] = (g == 0) ? cvt_pk2(b2[oo], b2[32 + oo]) : 0u;
        f.u[1] = 0u; f.u[2] = 0u; f.u[3] = 0u;
        bf1 = f.s;
    }

    const float4 w1a = *(const float4*)(w1 + g * 4);        // w1[0][g4..]
    const float4 w1b = *(const float4*)(w1 + 16 + g * 4);   // w1[1][g4..]
    const float4 b1v = *(const float4*)(b1 + g * 4);

    const int pairs = (E + 31) >> 5;
    for (int p = blockIdx.x; p < pairs; p += gridDim.x) {
        const int base = p * 32 + gsel * 16;
        const int edge = base + r16;
        const bool ev = edge < E;
        const int ec = ev ? edge : 0;

        int    src = ei[ec];
        float2 eav = *(const float2*)(ea + 2 * (size_t)ec);
        float2 xv  = *(const float2*)(x + 2 * (size_t)src);
        if (!ev) xv = make_float2(0.f, 0.f);

        float he0 = relu(fmaf(eav.x, w1a.x, fmaf(eav.y, w1b.x, b1v.x)));
        float he1 = relu(fmaf(eav.x, w1a.y, fmaf(eav.y, w1b.y, b1v.y)));
        float he2 = relu(fmaf(eav.x, w1a.z, fmaf(eav.y, w1b.z, b1v.z)));
        float he3 = relu(fmaf(eav.x, w1a.w, fmaf(eav.y, w1b.w, b1v.w)));

        frag_u a;
        a.u[0] = cvt_pk2(he0 * xv.x, he0 * xv.y);
        a.u[1] = cvt_pk2(he1 * xv.x, he1 * xv.y);
        a.u[2] = cvt_pk2(he2 * xv.x, he2 * xv.y);
        a.u[3] = cvt_pk2(he3 * xv.x, he3 * xv.y);
        f32x4 acc = {0.f, 0.f, 0.f, 0.f};
        acc = __builtin_amdgcn_mfma_f32_16x16x32_bf16(a.s, bf0, acc, 0, 0, 0);

        a.u[0] = (g == 0) ? cvt_pk2(xv.x, xv.y) : 0u;
        a.u[1] = 0u; a.u[2] = 0u; a.u[3] = 0u;
        acc = __builtin_amdgcn_mfma_f32_16x16x32_bf16(a.s, bf1, acc, 0, 0, 0);

        float* ap = agg + oo;
        if (base + g * 4 + 3 < E) {
            int4 d4 = *(const int4*)(ei + (size_t)E + base + g * 4);
            atomicAdd(ap + (size_t)d4.x * 32, acc[0]);
            atomicAdd(ap + (size_t)d4.y * 32, acc[1]);
            atomicAdd(ap + (size_t)d4.z * 32, acc[2]);
            atomicAdd(ap + (size_t)d4.w * 32, acc[3]);
        } else {
#pragma unroll
            for (int j = 0; j < 4; ++j) {
                int eg = base + g * 4 + j;
                if (eg < E) atomicAdd(ap + (size_t)ei[E + eg] * 32, acc[j]);
            }
        }
    }
}

// ---- node2 + fc2 (node1 fused): out = relu(agg2 + h1@root2 + b2)@fc2 + b --
__global__ __launch_bounds__(256) void node2_fused(
    const float* __restrict__ x,     // [N,2]
    const float* __restrict__ agg1,  // [N,32]
    const float* __restrict__ agg2,  // [N,32]
    const float* __restrict__ root1, // [2,32]
    const float* __restrict__ bias1, // [32]
    const float* __restrict__ root2, // [32,32]
    const float* __restrict__ bias2, // [32]
    const float* __restrict__ fc2w,  // [32,1]
    const float* __restrict__ fc2b,  // [1]
    float* __restrict__ out,         // [N]
    int N)
{
    __shared__ float s_r[1024];
    for (int t = threadIdx.x; t < 1024; t += blockDim.x) s_r[t] = root2[t];
    __syncthreads();

    int gid = blockIdx.x * blockDim.x + threadIdx.x;
    int n = gid >> 5, o = gid & 31;
    if (n >= N) return;

    float2 xv = *(const float2*)(x + 2 * (size_t)n);
    float h1o = relu(agg1[(size_t)n * 32 + o]
                   + xv.x * root1[o] + xv.y * root1[32 + o] + bias1[o]);

    float v = agg2[(size_t)n * 32 + o] + bias2[o];
#pragma unroll
    for (int i = 0; i < 32; ++i) {
        float hi = __shfl(h1o, i, 32);
        v = fmaf(hi, s_r[i * 32 + o], v);
    }
    v = relu(v);
    v *= fc2w[o];
#pragma unroll
    for (int off = 16; off; off >>= 1) v += __shfl_xor(v, off, 32);
    if (o == 0) out[n] = v + fc2b[0];
}

extern "C" void kernel_launch(void* const* d_in, const int* in_sizes, int n_in,
                              void* d_out, int out_size, void* d_ws, size_t ws_size,
                              hipStream_t stream) {
    const float* x      = (const float*)d_in[0];
    const int*   ei     = (const int*)  d_in[1];
    const float* ea     = (const float*)d_in[2];
    const float* nn1_w1 = (const float*)d_in[3];
    const float* nn1_b1 = (const float*)d_in[4];
    const float* nn1_w2 = (const float*)d_in[5];
    const float* nn1_b2 = (const float*)d_in[6];
    const float* root1  = (const float*)d_in[7];
    const float* bias1  = (const float*)d_in[8];
    const float* nn2_w1 = (const float*)d_in[9];
    const float* nn2_b1 = (const float*)d_in[10];
    const float* nn2_w2 = (const float*)d_in[11];
    const float* nn2_b2 = (const float*)d_in[12];
    const float* root2  = (const float*)d_in[13];
    const float* bias2  = (const float*)d_in[14];
    const float* fc2w   = (const float*)d_in[15];
    const float* fc2b   = (const float*)d_in[16];

    const int N = in_sizes[0] / 2;
    const int E = in_sizes[2] / 2;

    float* agg1 = (float*)d_ws;                  // [N,32]
    float* agg2 = agg1 + (size_t)N * 32;         // [N,32]

    hipMemsetAsync(d_ws, 0, (size_t)N * 64 * sizeof(float), stream);

    edge1_mfma<<<1024, 256, 0, stream>>>(
        x, ei, ea, nn1_w1, nn1_b1, nn1_w2, nn1_b2, agg1, E);

    edge2_fused<<<1024, 256, 0, stream>>>(
        x, agg1, ei, ea, root1, bias1,
        nn2_w1, nn2_b1, nn2_w2, nn2_b2, agg2, E);

    node2_fused<<<(N * 32 + 255) / 256, 256, 0, stream>>>(
        x, agg1, agg2, root1, bias1, root2, bias2, fc2w, fc2b,
        (float*)d_out, N);
}